// Round 10
// baseline (148.268 us; speedup 1.0000x reference)
//
#include <hip/hip_runtime.h>
#include <math.h>

// Problem dims (fixed by setup_inputs)
#define BBATCH 8
#define TT    4096
#define II    64
#define DD    128
#define OO    64
#define PP    8
#define NTOT  (BBATCH * TT)      // 32768
#define RPB   64                 // rows per block == scan chunk
#define NBLK  (NTOT / RPB)       // 512 blocks; <= resident capacity

// LDS layout (bytes)
#define PAN_H  0                 // h panel: 128 cols x 136 B (64 rows bf16 + pad)
#define PAN_Z  17408             // z panel: same (ends 34816)
#define HTB    34816             // scan out: 64 rows x 264 B bf16 (ends 51712)
#define LDSSZ  51712             // 163840/51712 = 3 blocks/CU; capacity >= 512

typedef short bf16x8 __attribute__((ext_vector_type(8)));
typedef float f32x4  __attribute__((ext_vector_type(4)));

__device__ __forceinline__ unsigned short f2bf(float f) {
    union { float f; unsigned int u; } v; v.f = f;
    unsigned int r = v.u + 0x7fffu + ((v.u >> 16) & 1u);   // RNE
    return (unsigned short)(r >> 16);
}

__device__ __forceinline__ float bf2f(unsigned short b) {
    union { float f; unsigned int u; } v; v.u = ((unsigned int)b) << 16;
    return v.f;
}

// pack the 8 piecewise-linear knot weights for one scalar into 8 bf16
// (A-fragment for mfma_16x16x32: k-block of 8 == one input's 8 knots)
__device__ __forceinline__ bf16x8 apl_frag(float xv) {
    float t = fminf(fmaxf((xv + 1.0f) * 3.5f, 0.0f), 7.0f);
    int idx = (int)t; if (idx > 6) idx = 6;
    float frac = t - (float)idx;
    const unsigned int b0 = f2bf(1.0f - frac);
    const unsigned int b1 = f2bf(frac);
    const int q = idx >> 1;
    const bool odd = (idx & 1) != 0;
    const unsigned int vA = odd ? (b0 << 16) : (b0 | (b1 << 16));
    const unsigned int vB = odd ? b1 : 0u;
    union { uint4 u; bf16x8 v; } cv;
    cv.u.x = (q == 0) ? vA : 0u;
    cv.u.y = (q == 1) ? vA : ((q == 0) ? vB : 0u);
    cv.u.z = (q == 2) ? vA : ((q == 1) ? vB : 0u);
    cv.u.w = (q == 3) ? vA : ((q == 2) ? vB : 0u);
    return cv.v;
}

// ---------------------------------------------------------------------------
// prep_tables: Vt[col][k] bf16 (256x512) from hv|zv; Ot[col][k] bf16 (64x1024)
// from ov.  Blocks 512..575 also zero the 512 lookback flags.
// ---------------------------------------------------------------------------
__global__ __launch_bounds__(256) void prep_tables(
    const float* __restrict__ hv, const float* __restrict__ zv,
    const float* __restrict__ ov,
    unsigned short* __restrict__ Vt, unsigned short* __restrict__ Ot,
    unsigned int* __restrict__ flags)
{
    const int b = blockIdx.x, tid = threadIdx.x;
    if (b < 512) {
        const int k = b, c = tid;
        float v = (c < 128) ? hv[(size_t)k * 128 + c] : zv[(size_t)k * 128 + (c - 128)];
        Vt[(size_t)c * 512 + k] = f2bf(v);
    } else {
        const int k = (b - 512) * 4 + (tid >> 6), c = tid & 63;
        Ot[(size_t)c * 1024 + k] = f2bf(ov[(size_t)k * 64 + c]);
        if (b < 576) flags[(size_t)(b - 512) * 256 + tid] = 0u;
    }
}

// ---------------------------------------------------------------------------
// Fused: APL1 GEMM (A-frags computed in-lane from x, B-frags loaded straight
// from global; NO staging, NO K-loop barriers) -> aggregates -> decoupled
// lookback -> prefix -> in-LDS z-mix scan (ht) -> APL2 GEMM (same trick) -> y.
// ---------------------------------------------------------------------------
__global__ __launch_bounds__(256, 2) void fused_all(
    const float* __restrict__ x, const float* __restrict__ h0,
    const unsigned short* __restrict__ Vt, const unsigned short* __restrict__ Ot,
    float* __restrict__ agg, unsigned int* __restrict__ flags,
    float* __restrict__ ht_out, float* __restrict__ y)
{
    __shared__ unsigned char smem[LDSSZ];
    const int tid = threadIdx.x;
    const int wave = tid >> 6, lane = tid & 63;
    const int m = lane & 15, u = lane >> 4;   // MFMA fragment coords
    const int g = blockIdx.x;                 // chunk id
    const int n0 = g * RPB;
    const int b = g >> 6, lb = g & 63;        // batch, local chunk (lb preds)

    // ---------------- Phase A: C(64 x 256) = W(64 x 512) x Vt^T -------------
    // lane (m,u), tile tr: A-frag = knots of x[n0 + tr*16 + m][c*4 + u]
    const int colbase = wave * 64;            // waves 0,1: h cols; 2,3: z cols
    f32x4 acc[4][4];
    #pragma unroll
    for (int tr = 0; tr < 4; ++tr)
        #pragma unroll
        for (int tc = 0; tc < 4; ++tc)
            acc[tr][tc] = (f32x4){0.f, 0.f, 0.f, 0.f};

    {
        const float* xb = x + (size_t)n0 * II + u;   // + row*II + c*4
        const unsigned char* vtb = (const unsigned char*)Vt + u * 16;
        for (int c = 0; c < 16; ++c) {
            bf16x8 a[4], bb[4];
            #pragma unroll
            for (int tr = 0; tr < 4; ++tr)
                a[tr] = apl_frag(xb[(size_t)(tr * 16 + m) * II + c * 4]);
            #pragma unroll
            for (int tc = 0; tc < 4; ++tc) {
                const int rc = colbase + tc * 16 + m;
                bb[tc] = *(const bf16x8*)(vtb + (size_t)rc * 1024 + c * 64);
            }
            #pragma unroll
            for (int tr = 0; tr < 4; ++tr)
                #pragma unroll
                for (int tc = 0; tc < 4; ++tc)
                    acc[tr][tc] = __builtin_amdgcn_mfma_f32_16x16x32_bf16(a[tr], bb[tc], acc[tr][tc], 0, 0, 0);
        }
    }

    // aggregates (waves 0,1 hold h cols 0..127) -> publish to global
    if (wave < 2) {
        #pragma unroll
        for (int tc = 0; tc < 4; ++tc) {
            float s = 0.0f;
            #pragma unroll
            for (int tr = 0; tr < 4; ++tr) {
                f32x4 v = acc[tr][tc];
                s += v[0] + v[1] + v[2] + v[3];
            }
            s += __shfl_xor(s, 16);
            s += __shfl_xor(s, 32);
            if ((lane >> 4) == 0)
                __hip_atomic_store(&agg[(size_t)g * 128 + colbase + tc * 16 + lane], s,
                                   __ATOMIC_RELAXED, __HIP_MEMORY_SCOPE_AGENT);
        }
    }

    // panels: C/D layout col=lane&15 (+tile), row=(lane>>4)*4+reg (+tile)
    #pragma unroll
    for (int tr = 0; tr < 4; ++tr) {
        #pragma unroll
        for (int tc = 0; tc < 4; ++tc) {
            const int col = colbase + tc * 16 + m;
            const int r0 = tr * 16 + u * 4;
            f32x4 v = acc[tr][tc];
            ushort4 p4;
            if (col < 128) {
                p4.x = f2bf(v[0]); p4.y = f2bf(v[1]);
                p4.z = f2bf(v[2]); p4.w = f2bf(v[3]);
                *(ushort4*)(smem + PAN_H + col * 136 + r0 * 2) = p4;
            } else {
                p4.x = f2bf(1.0f / (1.0f + __expf(-v[0])));
                p4.y = f2bf(1.0f / (1.0f + __expf(-v[1])));
                p4.z = f2bf(1.0f / (1.0f + __expf(-v[2])));
                p4.w = f2bf(1.0f / (1.0f + __expf(-v[3])));
                *(ushort4*)(smem + PAN_Z + (col - 128) * 136 + r0 * 2) = p4;
            }
        }
    }

    __syncthreads();                     // agg stores drained (vmcnt) + panels visible
    if (tid == 0) {
        __threadfence();
        __hip_atomic_store(&flags[(size_t)g * 32], 1u,
                           __ATOMIC_RELEASE, __HIP_MEMORY_SCOPE_AGENT);
    }

    // ---------- decoupled lookback: parallel poll of same-batch preds -------
    if (tid < lb) {
        const unsigned int* fp = flags + (size_t)(b * 64 + tid) * 32;
        while (__hip_atomic_load(fp, __ATOMIC_ACQUIRE, __HIP_MEMORY_SCOPE_AGENT) == 0u)
            __builtin_amdgcn_s_sleep(1);
    }
    __syncthreads();                     // all preds done

    // ---------------- prefix + in-LDS z-mix scan -> ht ----------------------
    if (tid < 128) {
        const int d = tid;
        float run = h0[(size_t)b * 128 + d];
        const float* ap = agg + (size_t)(b * 64) * 128 + d;
        float s0 = 0.f, s1 = 0.f, s2 = 0.f, s3 = 0.f;
        int k = 0;
        for (; k + 4 <= lb; k += 4) {
            s0 += __hip_atomic_load(ap + (size_t)(k + 0) * 128, __ATOMIC_RELAXED, __HIP_MEMORY_SCOPE_AGENT);
            s1 += __hip_atomic_load(ap + (size_t)(k + 1) * 128, __ATOMIC_RELAXED, __HIP_MEMORY_SCOPE_AGENT);
            s2 += __hip_atomic_load(ap + (size_t)(k + 2) * 128, __ATOMIC_RELAXED, __HIP_MEMORY_SCOPE_AGENT);
            s3 += __hip_atomic_load(ap + (size_t)(k + 3) * 128, __ATOMIC_RELAXED, __HIP_MEMORY_SCOPE_AGENT);
        }
        for (; k < lb; ++k)
            s0 += __hip_atomic_load(ap + (size_t)k * 128, __ATOMIC_RELAXED, __HIP_MEMORY_SCOPE_AGENT);
        run += (s0 + s1) + (s2 + s3);
        #pragma unroll
        for (int rq = 0; rq < 16; ++rq) {
            ushort4 h4 = *(const ushort4*)(smem + PAN_H + d * 136 + rq * 8);
            ushort4 z4 = *(const ushort4*)(smem + PAN_Z + d * 136 + rq * 8);
            const unsigned short* hp = (const unsigned short*)&h4;
            const unsigned short* zp = (const unsigned short*)&z4;
            #pragma unroll
            for (int kk = 0; kk < 4; ++kk) {
                const int r = rq * 4 + kk;
                float hb = bf2f(hp[kk]);
                float zt = bf2f(zp[kk]);
                run += hb;
                float htv = (1.0f - zt) * run + zt * hb;
                ht_out[(size_t)(n0 + r) * DD + d] = htv;
                *(unsigned short*)(smem + HTB + r * 264 + d * 2) = f2bf(htv);
            }
        }
    }
    __syncthreads();                     // HTB ready

    // ---------------- Phase C: y(64 x 64) = W2(64 x 1024) x Ot^T ------------
    // lane (m,u), tile tr: A-frag = knots of ht[row][d], d = c*8 + s*4 + u
    const int wr = wave >> 1, wc = wave & 1;
    f32x4 acc2[2][2];
    #pragma unroll
    for (int tr = 0; tr < 2; ++tr)
        #pragma unroll
        for (int tc = 0; tc < 2; ++tc)
            acc2[tr][tc] = (f32x4){0.f, 0.f, 0.f, 0.f};

    {
        const unsigned char* otb = (const unsigned char*)Ot + u * 16;
        for (int c = 0; c < 16; ++c) {
            #pragma unroll
            for (int s = 0; s < 2; ++s) {
                const int d = c * 8 + s * 4 + u;
                bf16x8 a2[2], b2[2];
                #pragma unroll
                for (int tr = 0; tr < 2; ++tr) {
                    const int r = wr * 32 + tr * 16 + m;
                    a2[tr] = apl_frag(bf2f(*(const unsigned short*)(smem + HTB + r * 264 + d * 2)));
                }
                #pragma unroll
                for (int tc = 0; tc < 2; ++tc) {
                    const int rc = wc * 32 + tc * 16 + m;
                    b2[tc] = *(const bf16x8*)(otb + (size_t)rc * 2048 + c * 128 + s * 64);
                }
                #pragma unroll
                for (int tr = 0; tr < 2; ++tr)
                    #pragma unroll
                    for (int tc = 0; tc < 2; ++tc)
                        acc2[tr][tc] = __builtin_amdgcn_mfma_f32_16x16x32_bf16(a2[tr], b2[tc], acc2[tr][tc], 0, 0, 0);
            }
        }
    }

    #pragma unroll
    for (int tr = 0; tr < 2; ++tr)
        #pragma unroll
        for (int tc = 0; tc < 2; ++tc) {
            const int col = wc * 32 + tc * 16 + m;
            const int n = n0 + wr * 32 + tr * 16 + u * 4;
            f32x4 v = acc2[tr][tc];
            #pragma unroll
            for (int rg = 0; rg < 4; ++rg)
                y[(size_t)(n + rg) * OO + col] = v[rg];
        }
}

// ---------------------------------------------------------------------------
extern "C" void kernel_launch(void* const* d_in, const int* in_sizes, int n_in,
                              void* d_out, int out_size, void* d_ws, size_t ws_size,
                              hipStream_t stream) {
    const float* x  = (const float*)d_in[0];   // (B,T,I)
    const float* h0 = (const float*)d_in[1];   // (B,D)
    const float* zv = (const float*)d_in[2];   // (I,P,D)
    const float* hv = (const float*)d_in[3];   // (I,P,D)
    const float* ov = (const float*)d_in[4];   // (D,P,O)

    float* y  = (float*)d_out;                           // (B,T,O)
    float* ht = (float*)d_out + (size_t)NTOT * OO;       // (B,T,D)

    unsigned int* flags = (unsigned int*)d_ws;                     // 512*32 u32
    float* agg = (float*)(flags + (size_t)NBLK * 32);              // 512*128 f32
    unsigned short* Vt = (unsigned short*)(agg + (size_t)NBLK * 128);  // 256x512
    unsigned short* Ot = Vt + 256 * 512;                               // 64x1024

    prep_tables<<<768, 256, 0, stream>>>(hv, zv, ov, Vt, Ot, flags);
    fused_all<<<NBLK, 256, 0, stream>>>(x, h0, Vt, Ot, agg, flags, ht, y);
}

// Round 11
// 130.757 us; speedup vs baseline: 1.1339x; 1.1339x over previous
//
#include <hip/hip_runtime.h>
#include <math.h>

// Problem dims (fixed by setup_inputs)
#define BBATCH 8
#define TT    4096
#define II    64
#define DD    128
#define OO    64
#define PP    8
#define NTOT  (BBATCH * TT)      // 32768
#define RPB   64                 // rows per block == scan chunk
#define NBLK  (NTOT / RPB)       // 512 blocks; == resident capacity (2/CU)

// LDS layout (bytes); regions reused across time-disjoint phases
#define PAN_H  0                 // h panel: 128 cols x 136 B (64 rows bf16 + pad)
#define PAN_Z  17408             // z panel: same (ends 34816)
#define XT     34816             // phase A: x-tile 64 rows x 136 B bf16 (ends 43520)
#define WVT    43520             // phase A: per-wave Vt dbuf 4w x 2 x 4096 (ends 76288)
#define HTB    34816             // scan/C: 64 rows x 264 B (over dead XT + WVT w0)
#define OTW    51712             // phase C: per-wave Ot dbuf 4w x 2 x 2048 (ends 68096)
#define LDSSZ  76288             // 2 blocks/CU -> grid 512 resident

typedef short bf16x8 __attribute__((ext_vector_type(8)));
typedef float f32x4  __attribute__((ext_vector_type(4)));

__device__ __forceinline__ unsigned short f2bf(float f) {
    union { float f; unsigned int u; } v; v.f = f;
    unsigned int r = v.u + 0x7fffu + ((v.u >> 16) & 1u);   // RNE
    return (unsigned short)(r >> 16);
}

__device__ __forceinline__ float bf2f(unsigned short b) {
    union { float f; unsigned int u; } v; v.u = ((unsigned int)b) << 16;
    return v.f;
}

__device__ __forceinline__ void gload_lds16(const void* g, void* l) {
    __builtin_amdgcn_global_load_lds(
        (const __attribute__((address_space(1))) unsigned int*)g,
        (__attribute__((address_space(3))) unsigned int*)l, 16, 0, 0);
}

// pack the 8 piecewise-linear knot weights for one scalar into 8 bf16
// (A-fragment k-block of 8 == one input's 8 knots)
__device__ __forceinline__ bf16x8 apl_frag(float xv) {
    float t = fminf(fmaxf((xv + 1.0f) * 3.5f, 0.0f), 7.0f);
    int idx = (int)t; if (idx > 6) idx = 6;
    float frac = t - (float)idx;
    const unsigned int b0 = f2bf(1.0f - frac);
    const unsigned int b1 = f2bf(frac);
    const int q = idx >> 1;
    const bool odd = (idx & 1) != 0;
    const unsigned int vA = odd ? (b0 << 16) : (b0 | (b1 << 16));
    const unsigned int vB = odd ? b1 : 0u;
    union { uint4 u; bf16x8 v; } cv;
    cv.u.x = (q == 0) ? vA : 0u;
    cv.u.y = (q == 1) ? vA : ((q == 0) ? vB : 0u);
    cv.u.z = (q == 2) ? vA : ((q == 1) ? vB : 0u);
    cv.u.w = (q == 3) ? vA : ((q == 2) ? vB : 0u);
    return cv.v;
}

// ---------------------------------------------------------------------------
// prep_tables: Vt[col][k] bf16 (256x512) from hv|zv; Ot[col][k] bf16 (64x1024)
// from ov.  Blocks 512..575 also zero the 512 lookback flags.
// ---------------------------------------------------------------------------
__global__ __launch_bounds__(256) void prep_tables(
    const float* __restrict__ hv, const float* __restrict__ zv,
    const float* __restrict__ ov,
    unsigned short* __restrict__ Vt, unsigned short* __restrict__ Ot,
    unsigned int* __restrict__ flags)
{
    const int b = blockIdx.x, tid = threadIdx.x;
    if (b < 512) {
        const int k = b, c = tid;
        float v = (c < 128) ? hv[(size_t)k * 128 + c] : zv[(size_t)k * 128 + (c - 128)];
        Vt[(size_t)c * 512 + k] = f2bf(v);
    } else {
        const int k = (b - 512) * 4 + (tid >> 6), c = tid & 63;
        Ot[(size_t)c * 1024 + k] = f2bf(ov[(size_t)k * 64 + c]);
        if (b < 576) flags[(size_t)(b - 512) * 256 + tid] = 0u;
    }
}

// ---------------------------------------------------------------------------
// Fused: APL1 GEMM (wave-private staging, barrier-free K-loop with
// s_waitcnt vmcnt(N)) -> aggregates -> decoupled lookback -> prefix ->
// in-LDS z-mix scan (ht) -> APL2 GEMM (same trick) -> y.
// ---------------------------------------------------------------------------
__global__ __launch_bounds__(256, 2) void fused_all(
    const float* __restrict__ x, const float* __restrict__ h0,
    const unsigned short* __restrict__ Vt, const unsigned short* __restrict__ Ot,
    float* __restrict__ agg, unsigned int* __restrict__ flags,
    float* __restrict__ ht_out, float* __restrict__ y)
{
    __shared__ unsigned char smem[LDSSZ];
    const int tid = threadIdx.x;
    const int wave = tid >> 6, lane = tid & 63;
    const int m = lane & 15, u = lane >> 4;   // MFMA fragment coords
    const int g = blockIdx.x;                 // chunk id
    const int n0 = g * RPB;
    const int b = g >> 6, lb = g & 63;        // batch, local chunk (lb preds)

    // ---- stage x-tile (64 rows x 64 fp32 -> bf16) into XT, coalesced ----
    {
        const int row = tid >> 2, c0 = (tid & 3) * 16;
        const float* xr = x + (size_t)(n0 + row) * II + c0;
        #pragma unroll
        for (int j = 0; j < 4; ++j) {
            float4 v = *(const float4*)(xr + 4 * j);
            ushort4 p;
            p.x = f2bf(v.x); p.y = f2bf(v.y); p.z = f2bf(v.z); p.w = f2bf(v.w);
            *(ushort4*)(smem + XT + row * 136 + (c0 + 4 * j) * 2) = p;
        }
    }

    // wave-private Vt staging: wave stages exactly its own 64 cols
    auto stageVtW = [&](int c, int bi) {
        unsigned char* dst = smem + WVT + wave * 8192 + bi * 4096;
        #pragma unroll
        for (int j = 0; j < 4; ++j)
            gload_lds16((const unsigned char*)Vt
                            + (size_t)(wave * 64 + j * 16 + (lane >> 2)) * 1024
                            + c * 64 + (lane & 3) * 16,
                        dst + j * 1024);
    };

    stageVtW(0, 0);
    __syncthreads();   // x-tile visible to all waves (also drains chunk-0 DMA)

    // ---------------- Phase A: C(64 x 256) = W(64 x 512) x Vt^T -------------
    const int colbase = wave * 64;            // waves 0,1: h cols; 2,3: z cols
    f32x4 acc[4][4];
    #pragma unroll
    for (int tr = 0; tr < 4; ++tr)
        #pragma unroll
        for (int tc = 0; tc < 4; ++tc)
            acc[tr][tc] = (f32x4){0.f, 0.f, 0.f, 0.f};

    for (int c = 0; c < 16; ++c) {
        if (c < 15) {
            stageVtW(c + 1, (c + 1) & 1);
            __builtin_amdgcn_s_waitcnt(0x0F74);   // vmcnt(4): chunk c landed, prefetch in flight
        } else {
            __builtin_amdgcn_s_waitcnt(0x0F70);   // vmcnt(0): last chunk
        }
        const unsigned char* vb = smem + WVT + wave * 8192 + (c & 1) * 4096;
        bf16x8 a[4], bb[4];
        #pragma unroll
        for (int tr = 0; tr < 4; ++tr) {
            float xv = bf2f(*(const unsigned short*)(smem + XT + (tr * 16 + m) * 136 + (c * 4 + u) * 2));
            a[tr] = apl_frag(xv);
        }
        #pragma unroll
        for (int tc = 0; tc < 4; ++tc)
            bb[tc] = *(const bf16x8*)(vb + (tc * 16 + m) * 64 + u * 16);
        #pragma unroll
        for (int tr = 0; tr < 4; ++tr)
            #pragma unroll
            for (int tc = 0; tc < 4; ++tc)
                acc[tr][tc] = __builtin_amdgcn_mfma_f32_16x16x32_bf16(a[tr], bb[tc], acc[tr][tc], 0, 0, 0);
    }

    // aggregates (waves 0,1 hold h cols 0..127) -> publish to global
    if (wave < 2) {
        #pragma unroll
        for (int tc = 0; tc < 4; ++tc) {
            float s = 0.0f;
            #pragma unroll
            for (int tr = 0; tr < 4; ++tr) {
                f32x4 v = acc[tr][tc];
                s += v[0] + v[1] + v[2] + v[3];
            }
            s += __shfl_xor(s, 16);
            s += __shfl_xor(s, 32);
            if ((lane >> 4) == 0)
                __hip_atomic_store(&agg[(size_t)g * 128 + colbase + tc * 16 + lane], s,
                                   __ATOMIC_RELAXED, __HIP_MEMORY_SCOPE_AGENT);
        }
    }

    // panels: C/D layout col=lane&15 (+tile), row=(lane>>4)*4+reg (+tile)
    #pragma unroll
    for (int tr = 0; tr < 4; ++tr) {
        #pragma unroll
        for (int tc = 0; tc < 4; ++tc) {
            const int col = colbase + tc * 16 + m;
            const int r0 = tr * 16 + u * 4;
            f32x4 v = acc[tr][tc];
            ushort4 p4;
            if (col < 128) {
                p4.x = f2bf(v[0]); p4.y = f2bf(v[1]);
                p4.z = f2bf(v[2]); p4.w = f2bf(v[3]);
                *(ushort4*)(smem + PAN_H + col * 136 + r0 * 2) = p4;
            } else {
                p4.x = f2bf(1.0f / (1.0f + __expf(-v[0])));
                p4.y = f2bf(1.0f / (1.0f + __expf(-v[1])));
                p4.z = f2bf(1.0f / (1.0f + __expf(-v[2])));
                p4.w = f2bf(1.0f / (1.0f + __expf(-v[3])));
                *(ushort4*)(smem + PAN_Z + (col - 128) * 136 + r0 * 2) = p4;
            }
        }
    }

    __syncthreads();                     // agg stores drained + panels visible
    if (tid == 0) {
        __threadfence();
        __hip_atomic_store(&flags[(size_t)g * 32], 1u,
                           __ATOMIC_RELEASE, __HIP_MEMORY_SCOPE_AGENT);
    }

    // wave-private Ot staging (wc = wave&1 selects the 32 cols this wave uses)
    auto stageOtW = [&](int c, int bi) {
        unsigned char* dst = smem + OTW + wave * 4096 + bi * 2048;
        #pragma unroll
        for (int j = 0; j < 2; ++j)
            gload_lds16((const unsigned char*)Ot
                            + (size_t)((wave & 1) * 32 + j * 16 + (lane >> 2)) * 2048
                            + c * 64 + (lane & 3) * 16,
                        dst + j * 1024);
    };

    // kick off Ot chunk-0 DMA (overlaps poll/prefix/scan; WVT region dead for
    // all waves past the barrier above)
    stageOtW(0, 0);

    // ---------- decoupled lookback: parallel poll of same-batch preds -------
    if (tid < lb) {
        const unsigned int* fp = flags + (size_t)(b * 64 + tid) * 32;
        while (__hip_atomic_load(fp, __ATOMIC_ACQUIRE, __HIP_MEMORY_SCOPE_AGENT) == 0u)
            __builtin_amdgcn_s_sleep(1);
    }
    __syncthreads();                     // all preds done

    // ---------------- prefix + in-LDS z-mix scan -> ht ----------------------
    if (tid < 128) {
        const int d = tid;
        float run = h0[(size_t)b * 128 + d];
        const float* ap = agg + (size_t)(b * 64) * 128 + d;
        float s0 = 0.f, s1 = 0.f, s2 = 0.f, s3 = 0.f;
        int k = 0;
        for (; k + 4 <= lb; k += 4) {
            s0 += __hip_atomic_load(ap + (size_t)(k + 0) * 128, __ATOMIC_RELAXED, __HIP_MEMORY_SCOPE_AGENT);
            s1 += __hip_atomic_load(ap + (size_t)(k + 1) * 128, __ATOMIC_RELAXED, __HIP_MEMORY_SCOPE_AGENT);
            s2 += __hip_atomic_load(ap + (size_t)(k + 2) * 128, __ATOMIC_RELAXED, __HIP_MEMORY_SCOPE_AGENT);
            s3 += __hip_atomic_load(ap + (size_t)(k + 3) * 128, __ATOMIC_RELAXED, __HIP_MEMORY_SCOPE_AGENT);
        }
        for (; k < lb; ++k)
            s0 += __hip_atomic_load(ap + (size_t)k * 128, __ATOMIC_RELAXED, __HIP_MEMORY_SCOPE_AGENT);
        run += (s0 + s1) + (s2 + s3);
        #pragma unroll
        for (int rq = 0; rq < 16; ++rq) {
            ushort4 h4 = *(const ushort4*)(smem + PAN_H + d * 136 + rq * 8);
            ushort4 z4 = *(const ushort4*)(smem + PAN_Z + d * 136 + rq * 8);
            const unsigned short* hp = (const unsigned short*)&h4;
            const unsigned short* zp = (const unsigned short*)&z4;
            #pragma unroll
            for (int kk = 0; kk < 4; ++kk) {
                const int r = rq * 4 + kk;
                float hb = bf2f(hp[kk]);
                float zt = bf2f(zp[kk]);
                run += hb;
                float htv = (1.0f - zt) * run + zt * hb;
                ht_out[(size_t)(n0 + r) * DD + d] = htv;
                *(unsigned short*)(smem + HTB + r * 264 + d * 2) = f2bf(htv);
            }
        }
    }
    __syncthreads();                     // HTB ready; ht stores drained

    // ---------------- Phase C: y(64 x 64) = W2(64 x 1024) x Ot^T ------------
    // 32 chunks of K=32 (4 inputs each); barrier-free, wave-private staging
    const int wr = wave >> 1, wc = wave & 1;
    f32x4 acc2[2][2];
    #pragma unroll
    for (int tr = 0; tr < 2; ++tr)
        #pragma unroll
        for (int tc = 0; tc < 2; ++tc)
            acc2[tr][tc] = (f32x4){0.f, 0.f, 0.f, 0.f};

    for (int c = 0; c < 32; ++c) {
        if (c < 31) {
            stageOtW(c + 1, (c + 1) & 1);
            __builtin_amdgcn_s_waitcnt(0x0F72);   // vmcnt(2): chunk c landed
        } else {
            __builtin_amdgcn_s_waitcnt(0x0F70);
        }
        const unsigned char* ob = smem + OTW + wave * 4096 + (c & 1) * 2048;
        bf16x8 a2[2], b2[2];
        #pragma unroll
        for (int tr = 0; tr < 2; ++tr) {
            const int r = wr * 32 + tr * 16 + m;
            float htv = bf2f(*(const unsigned short*)(smem + HTB + r * 264 + (c * 4 + u) * 2));
            a2[tr] = apl_frag(htv);
        }
        #pragma unroll
        for (int tc = 0; tc < 2; ++tc)
            b2[tc] = *(const bf16x8*)(ob + (tc * 16 + m) * 64 + u * 16);
        #pragma unroll
        for (int tr = 0; tr < 2; ++tr)
            #pragma unroll
            for (int tc = 0; tc < 2; ++tc)
                acc2[tr][tc] = __builtin_amdgcn_mfma_f32_16x16x32_bf16(a2[tr], b2[tc], acc2[tr][tc], 0, 0, 0);
    }

    #pragma unroll
    for (int tr = 0; tr < 2; ++tr)
        #pragma unroll
        for (int tc = 0; tc < 2; ++tc) {
            const int col = wc * 32 + tc * 16 + m;
            const int n = n0 + wr * 32 + tr * 16 + u * 4;
            f32x4 v = acc2[tr][tc];
            #pragma unroll
            for (int rg = 0; rg < 4; ++rg)
                y[(size_t)(n + rg) * OO + col] = v[rg];
        }
}

// ---------------------------------------------------------------------------
extern "C" void kernel_launch(void* const* d_in, const int* in_sizes, int n_in,
                              void* d_out, int out_size, void* d_ws, size_t ws_size,
                              hipStream_t stream) {
    const float* x  = (const float*)d_in[0];   // (B,T,I)
    const float* h0 = (const float*)d_in[1];   // (B,D)
    const float* zv = (const float*)d_in[2];   // (I,P,D)
    const float* hv = (const float*)d_in[3];   // (I,P,D)
    const float* ov = (const float*)d_in[4];   // (D,P,O)

    float* y  = (float*)d_out;                           // (B,T,O)
    float* ht = (float*)d_out + (size_t)NTOT * OO;       // (B,T,D)

    unsigned int* flags = (unsigned int*)d_ws;                     // 512*32 u32
    float* agg = (float*)(flags + (size_t)NBLK * 32);              // 512*128 f32
    unsigned short* Vt = (unsigned short*)(agg + (size_t)NBLK * 128);  // 256x512
    unsigned short* Ot = Vt + 256 * 512;                               // 64x1024

    prep_tables<<<768, 256, 0, stream>>>(hv, zv, ov, Vt, Ot, flags);
    fused_all<<<NBLK, 256, 0, stream>>>(x, h0, Vt, Ot, agg, flags, ht, y);
}